// Round 2
// baseline (1130.387 us; speedup 1.0000x reference)
//
#include <hip/hip_runtime.h>
#include <stdint.h>

// Stage1Assigner (RPN matcher + subsample + top-k per GT) for MI355X.
// B=8 images, A=200000 anchors, G=64 GTs, K=4, thresholds 0.3/0.7, 128 max pos.
//
// PRNG: JAX threefry with jax_threefry_partitionable=True (modern default):
//   keys[b]  = threefry2x32((0,42), (0,b))          (fold-like split)
//   bits[a]  = y0 ^ y1, (y0,y1)=threefry2x32(key_b, (0,a))   (XOR-folded counter mode)
//   r[a]     = bitcast((bits>>9)|0x3f800000) - 1    (monotone in bits>>9)
// Selection of 128 positives = 128 lexicographically smallest (bits>>9, a).
//
// Pipeline (bounded ~1.8MB workspace):
//   k_top4    per (b,g) top-4 anchors by IoU (ties -> smaller idx); top1 = hq
//   k_anchor  per anchor: argmax gt, pos = (max>=0.7 | iou==hq[g] any g);
//             flag byte (pos<<6|g); npos; histogram of rbits23>>11 (4096 bins)
//   k_bin     per image: find target bin tb + count-before (or select-all if n<=128)
//   k_collect positives in bin tb -> fine list of 29-bit keys ((rbits&0x7ff)<<18|a)
//   k_tstar   per image: exact 128th-smallest threshold T* (41-bit key)
//   k_count   positives with key<=T* -> per-gt counts
//   k_out     emit (pr, gt, valid, scores) from top4 + counts
//
// IoU is fp-contract(off) IEEE per-op: identical bits in both IoU passes and
// matches XLA's per-HLO rounding (XLA does not fuse separate mul/add HLOs).

#pragma clang fp contract(off)

#define B_IMG 8
#define A_N 200000
#define G_N 64
#define K_TOP 4
#define MAX_POS 128
#define NBIN 4096
#define FINE_CAP 4096

typedef unsigned long long u64;
typedef unsigned int u32;
typedef unsigned char u8;

__device__ __forceinline__ u32 rotl32(u32 v, int n) { return (v << n) | (v >> (32 - n)); }

__device__ __forceinline__ void tf_round(u32& x0, u32& x1, int r) {
  x0 += x1; x1 = rotl32(x1, r); x1 ^= x0;
}

// JAX threefry2x32 block cipher (20 rounds).
__device__ __forceinline__ void threefry2x32(u32 k0, u32 k1, u32& x0, u32& x1) {
  u32 ks2 = 0x1BD11BDAu ^ k0 ^ k1;
  x0 += k0; x1 += k1;
  tf_round(x0,x1,13); tf_round(x0,x1,15); tf_round(x0,x1,26); tf_round(x0,x1,6);
  x0 += k1; x1 += ks2 + 1u;
  tf_round(x0,x1,17); tf_round(x0,x1,29); tf_round(x0,x1,16); tf_round(x0,x1,24);
  x0 += ks2; x1 += k0 + 2u;
  tf_round(x0,x1,13); tf_round(x0,x1,15); tf_round(x0,x1,26); tf_round(x0,x1,6);
  x0 += k0; x1 += k1 + 3u;
  tf_round(x0,x1,17); tf_round(x0,x1,29); tf_round(x0,x1,16); tf_round(x0,x1,24);
  x0 += k1; x1 += ks2 + 4u;
  tf_round(x0,x1,13); tf_round(x0,x1,15); tf_round(x0,x1,26); tf_round(x0,x1,6);
  x0 += ks2; x1 += k0 + 5u;
}

// Partitionable fold-like split: keys[b] = threefry2x32((0,42),(0,b)), both words.
__device__ __forceinline__ void image_key(int b, u32& kb0, u32& kb1) {
  u32 x0 = 0u, x1 = (u32)b;
  threefry2x32(0u, 42u, x0, x1);
  kb0 = x0; kb1 = x1;
}

// Partitionable 32-bit random bits: XOR of both cipher outputs on counter (0,a).
__device__ __forceinline__ u32 rbits_for(u32 k0, u32 k1, u32 a) {
  u32 x0 = 0u, x1 = a;
  threefry2x32(k0, k1, x0, x1);
  return x0 ^ x1;
}

// cxcywh -> xyxy + area, exactly as reference.
__device__ __forceinline__ void conv_box(float4 bx, float& x0, float& y0,
                                         float& x1, float& y1, float& area) {
  #pragma clang fp contract(off)
  x0 = bx.x - 0.5f * bx.z;
  y0 = bx.y - 0.5f * bx.w;
  x1 = bx.x + 0.5f * bx.z;
  y1 = bx.y + 0.5f * bx.w;
  area = (x1 - x0) * (y1 - y0);
}

__device__ __forceinline__ float iou_pair(float ax0, float ay0, float ax1, float ay1, float aarea,
                                          float gx0, float gy0, float gx1, float gy1, float garea) {
  #pragma clang fp contract(off)
  float ltx = fmaxf(gx0, ax0), lty = fmaxf(gy0, ay0);
  float rbx = fminf(gx1, ax1), rby = fminf(gy1, ay1);
  float w = fmaxf(rbx - ltx, 0.0f), h = fmaxf(rby - lty, 0.0f);
  float inter = w * h;
  float uni = (garea + aarea) - inter;
  return inter / uni;
}

// ---------------- Kernel 1: per-(b,g) top-4 ----------------
// grid (G/4, B), block 256 = 4 waves; wave w handles gt 4*blockIdx.x+w.
__launch_bounds__(256)
__global__ void k_top4(const float4* __restrict__ anchors, const float4* __restrict__ gt,
                       u64* __restrict__ top4) {
  const int b = blockIdx.y;
  const int t = threadIdx.x;
  const int wave = t >> 6, lane = t & 63;
  const int g = blockIdx.x * 4 + wave;

  __shared__ float4 sxy[1024];
  __shared__ float  sar[1024];

  float gx0, gy0, gx1, gy1, garea;
  {
    float4 gb = gt[(size_t)b * G_N + g];
    conv_box(gb, gx0, gy0, gx1, gy1, garea);
  }

  u64 top[4] = {0ull, 0ull, 0ull, 0ull};
  const float4* ab = anchors + (size_t)b * A_N;

  for (int tb = 0; tb < A_N; tb += 1024) {
    #pragma unroll
    for (int j = 0; j < 4; j++) {
      int idx = tb + t + 256 * j;
      if (idx < A_N) {
        float x0, y0, x1, y1, ar;
        conv_box(ab[idx], x0, y0, x1, y1, ar);
        sxy[t + 256 * j] = make_float4(x0, y0, x1, y1);
        sar[t + 256 * j] = ar;
      }
    }
    __syncthreads();
    const int cnt = min(1024, A_N - tb);
    #pragma unroll 4
    for (int j = 0; j < 16; j++) {
      int ii = lane + 64 * j;
      if (ii < cnt) {
        float4 x = sxy[ii];
        float v = iou_pair(x.x, x.y, x.z, x.w, sar[ii], gx0, gy0, gx1, gy1, garea);
        u32 aidx = (u32)(tb + ii);
        u64 key = ((u64)__float_as_uint(v) << 32) | (u64)(~aidx);  // ties -> smaller idx
        if (key > top[3]) {
          if (key > top[0])      { top[3]=top[2]; top[2]=top[1]; top[1]=top[0]; top[0]=key; }
          else if (key > top[1]) { top[3]=top[2]; top[2]=top[1]; top[1]=key; }
          else if (key > top[2]) { top[3]=top[2]; top[2]=key; }
          else                   { top[3]=key; }
        }
      }
    }
    __syncthreads();
  }

  for (int off = 32; off >= 1; off >>= 1) {
    u64 o[4];
    #pragma unroll
    for (int k = 0; k < 4; k++) o[k] = __shfl_down(top[k], (unsigned)off);
    u64 m[4]; int i = 0, j = 0;
    #pragma unroll
    for (int k = 0; k < 4; k++) m[k] = (top[i] >= o[j]) ? top[i++] : o[j++];
    #pragma unroll
    for (int k = 0; k < 4; k++) top[k] = m[k];
  }
  if (lane == 0) {
    u64* dst = top4 + ((size_t)b * G_N + g) * 4;
    #pragma unroll
    for (int k = 0; k < 4; k++) dst[k] = top[k];
  }
}

// ---------------- Kernel 2: per-anchor pass ----------------
__launch_bounds__(256)
__global__ void k_anchor(const float4* __restrict__ anchors, const float4* __restrict__ gt,
                         const u64* __restrict__ top4, u8* __restrict__ flagg,
                         u32* __restrict__ npos, u32* __restrict__ hist) {
  const int b = blockIdx.y;
  const int t = threadIdx.x;
  __shared__ float sgx0[64], sgy0[64], sgx1[64], sgy1[64], sga[64];
  __shared__ u32 shq[64];
  __shared__ u32 skey[2];

  if (t < 64) {
    float x0, y0, x1, y1, ar;
    conv_box(gt[(size_t)b * G_N + t], x0, y0, x1, y1, ar);
    sgx0[t] = x0; sgy0[t] = y0; sgx1[t] = x1; sgy1[t] = y1; sga[t] = ar;
    shq[t] = (u32)(top4[((size_t)b * G_N + t) * 4] >> 32);  // hq bits
  }
  if (t == 0) { u32 k0, k1; image_key(b, k0, k1); skey[0] = k0; skey[1] = k1; }
  __syncthreads();

  const int a = blockIdx.x * 256 + t;
  if (a >= A_N) return;

  float ax0, ay0, ax1, ay1, aar;
  conv_box(anchors[(size_t)b * A_N + a], ax0, ay0, ax1, ay1, aar);

  float bv = -1.0f;
  int g0 = 0;
  bool lq = false;
  for (int g = 0; g < 64; g++) {
    float i0 = iou_pair(ax0, ay0, ax1, ay1, aar,
                        sgx0[g], sgy0[g], sgx1[g], sgy1[g], sga[g]);
    if (i0 > bv) { bv = i0; g0 = g; }     // strict > keeps first max (jnp.argmax)
    lq |= (i0 == __uint_as_float(shq[g]));
  }
  bool pos = (bv >= 0.7f) || lq;
  flagg[(size_t)b * A_N + a] = (u8)((pos ? 0x40 : 0) | g0);
  if (pos) {
    atomicAdd(&npos[b], 1u);
    u32 bits = rbits_for(skey[0], skey[1], (u32)a);
    atomicAdd(&hist[b * NBIN + (int)(bits >> 20)], 1u);  // bin = rbits23 >> 11
  }
}

// ---------------- Kernel 3: per-image target bin ----------------
__launch_bounds__(256)
__global__ void k_bin(const u32* __restrict__ npos, const u32* __restrict__ hist,
                      int2* __restrict__ binsel) {
  const int b = blockIdx.x;
  const int t = threadIdx.x;
  __shared__ u32 part[256];
  const u32* hb = hist + b * NBIN;
  u32 local = 0;
  for (int j = 0; j < 16; j++) local += hb[t * 16 + j];
  part[t] = local;
  __syncthreads();
  if (t == 0) {
    if (npos[b] <= MAX_POS) {
      binsel[b] = make_int2(-1, 0);
    } else {
      u32 cum = 0; int chunk = 0;
      for (int i = 0; i < 256; i++) {
        if (cum + part[i] >= MAX_POS) { chunk = i; break; }
        cum += part[i];
      }
      int tb = chunk * 16; u32 before = cum;
      for (int j = 0; j < 16; j++) {
        u32 h = hb[chunk * 16 + j];
        if (before + h >= MAX_POS) { tb = chunk * 16 + j; break; }
        before += h;
      }
      binsel[b] = make_int2(tb, (int)before);
    }
  }
}

// ---------------- Kernel 4: collect fine candidates in target bin ----------------
__launch_bounds__(256)
__global__ void k_collect(const u8* __restrict__ flagg, const int2* __restrict__ binsel,
                          u32* __restrict__ fine, u32* __restrict__ fcnt) {
  const int b = blockIdx.y;
  __shared__ u32 sk0, sk1; __shared__ int stb;
  if (threadIdx.x == 0) {
    u32 k0, k1; image_key(b, k0, k1); sk0 = k0; sk1 = k1;
    stb = binsel[b].x;
  }
  __syncthreads();
  if (stb < 0) return;
  const int a = blockIdx.x * 256 + threadIdx.x;
  if (a >= A_N) return;
  u8 f = flagg[(size_t)b * A_N + a];
  if (!(f & 0x40)) return;
  u32 r23 = rbits_for(sk0, sk1, (u32)a) >> 9;
  if ((int)(r23 >> 11) != stb) return;
  u32 key = ((r23 & 0x7FFu) << 18) | (u32)a;   // 29-bit fine key
  u32 i = atomicAdd(&fcnt[b], 1u);
  if (i < FINE_CAP) fine[b * FINE_CAP + i] = key;
}

// ---------------- Kernel 5: exact 128th-smallest threshold ----------------
__launch_bounds__(256)
__global__ void k_tstar(const int2* __restrict__ binsel, const u32* __restrict__ fine,
                        const u32* __restrict__ fcnt, u64* __restrict__ Tstar) {
  const int b = blockIdx.x;
  const int t = threadIdx.x;
  __shared__ u32 sred[256];
  int2 bs = binsel[b];
  if (bs.x < 0) { if (t == 0) Tstar[b] = ~0ull; return; }
  const int m = min((int)fcnt[b], FINE_CAP);
  const u32 need = (u32)(MAX_POS - bs.y);   // >= 1
  const u32* fb = fine + b * FINE_CAP;
  u32 lo = 0, hi = (1u << 29) - 1;
  while (lo < hi) {
    u32 mid = lo + ((hi - lo) >> 1);
    u32 local = 0;
    for (int j = t; j < m; j += 256) local += (fb[j] <= mid) ? 1u : 0u;
    sred[t] = local;
    __syncthreads();
    for (int s = 128; s > 0; s >>= 1) { if (t < s) sred[t] += sred[t + s]; __syncthreads(); }
    u32 c = sred[0];
    __syncthreads();
    if (c >= need) hi = mid; else lo = mid + 1;
  }
  if (t == 0) Tstar[b] = ((u64)(u32)bs.x << 29) | (u64)lo;   // 41-bit threshold
}

// ---------------- Kernel 6: per-gt counts of selected positives ----------------
__launch_bounds__(256)
__global__ void k_count(const u8* __restrict__ flagg, const u64* __restrict__ Tstar,
                        u32* __restrict__ cnt) {
  const int b = blockIdx.y;
  __shared__ u32 sk0, sk1; __shared__ u64 sT;
  if (threadIdx.x == 0) {
    u32 k0, k1; image_key(b, k0, k1); sk0 = k0; sk1 = k1;
    sT = Tstar[b];
  }
  __syncthreads();
  const int a = blockIdx.x * 256 + threadIdx.x;
  if (a >= A_N) return;
  u8 f = flagg[(size_t)b * A_N + a];
  if (!(f & 0x40)) return;
  u64 fk = 0;
  if (sT != ~0ull) {
    u32 r23 = rbits_for(sk0, sk1, (u32)a) >> 9;
    fk = ((u64)r23 << 18) | (u64)(u32)a;   // 41-bit full key
  }
  if (fk <= sT) atomicAdd(&cnt[b * G_N + (f & 63)], 1u);
}

// ---------------- Kernel 7: output ----------------
__launch_bounds__(64)
__global__ void k_out(const u64* __restrict__ top4, const u32* __restrict__ cnt,
                      float* __restrict__ out, int sec) {
  const int b = blockIdx.x;
  const int g = threadIdx.x;   // 64 threads
  const u32 c = min(cnt[b * G_N + g], (u32)K_TOP);
  const u64* t4 = top4 + ((size_t)b * G_N + g) * 4;
  #pragma unroll
  for (int k = 0; k < 4; k++) {
    u64 key = t4[k];
    u32 fb = (u32)(key >> 32);
    u32 aidx = ~(u32)key;
    bool valid = (u32)k < c;
    int o = b * (G_N * K_TOP) + g * K_TOP + k;
    out[0 * sec + o] = valid ? (float)aidx : -1.0f;          // pr_inds
    out[1 * sec + o] = valid ? (float)g : -1.0f;             // gt_inds
    out[2 * sec + o] = valid ? 1.0f : 0.0f;                  // valid mask
    out[3 * sec + o] = valid ? __uint_as_float(fb) : 0.0f;   // topk ious
  }
}

extern "C" void kernel_launch(void* const* d_in, const int* in_sizes, int n_in,
                              void* d_out, int out_size, void* d_ws, size_t ws_size,
                              hipStream_t stream) {
  const float4* anchors = (const float4*)d_in[0];  // [B, A, 4] cxcywh
  const float4* gt      = (const float4*)d_in[1];  // [B, G, 4] cxcywh
  float* out = (float*)d_out;                      // 4 x [B, G*K] concatenated

  char* ws = (char*)d_ws;
  u64*  top4   = (u64*)(ws);                       // 16384 B
  int2* binsel = (int2*)(ws + 16384);              // 64 B
  u64*  Tstar  = (u64*)(ws + 16448);               // 64 B
  u32*  fine   = (u32*)(ws + 16512);               // B*FINE_CAP*4 = 131072 B
  u8*   flagg  = (u8*)(ws + 147584);               // B*A = 1600000 B
  char* zr     = ws + 1747584;                     // zeroed region, 133184 B
  u32*  npos   = (u32*)(zr);                       // 32 B
  u32*  fcnt   = (u32*)(zr + 32);                  // 32 B
  u32*  cnt    = (u32*)(zr + 64);                  // B*G*4 = 2048 B
  u32*  hist   = (u32*)(zr + 2112);                // B*NBIN*4 = 131072 B

  hipMemsetAsync(zr, 0, 133184, stream);

  const int ABLK = (A_N + 255) / 256;  // 782
  int sec = out_size / 4;              // 2048 = B*G*K

  k_top4   <<<dim3(G_N / 4, B_IMG), 256, 0, stream>>>(anchors, gt, top4);
  k_anchor <<<dim3(ABLK, B_IMG), 256, 0, stream>>>(anchors, gt, top4, flagg, npos, hist);
  k_bin    <<<dim3(B_IMG), 256, 0, stream>>>(npos, hist, binsel);
  k_collect<<<dim3(ABLK, B_IMG), 256, 0, stream>>>(flagg, binsel, fine, fcnt);
  k_tstar  <<<dim3(B_IMG), 256, 0, stream>>>(binsel, fine, fcnt, Tstar);
  k_count  <<<dim3(ABLK, B_IMG), 256, 0, stream>>>(flagg, Tstar, cnt);
  k_out    <<<dim3(B_IMG), 64, 0, stream>>>(top4, cnt, out, sec);
}

// Round 3
// 674.064 us; speedup vs baseline: 1.6770x; 1.6770x over previous
//
#include <hip/hip_runtime.h>
#include <stdint.h>

// Stage1Assigner (RPN matcher + subsample + top-k per GT) for MI355X.
// B=8 images, A=200000 anchors, G=64 GTs, K=4, thresholds 0.3/0.7, 128 max pos.
//
// PRNG: JAX threefry, jax_threefry_partitionable=True (modern default):
//   keys[b] = threefry2x32((0,42),(0,b));  bits[a] = y0^y1 of threefry2x32(key_b,(0,a))
// Selection of 128 positives = 128 lexicographically smallest (bits>>9, a).
//
// Pipeline:
//   k_top4_part  per (slice,b): per-gt top-4 over a 2048-anchor LDS-staged slice
//   k_top4_merge per (b,g): merge 98 partial top-4 lists -> top4 (hq = top1)
//   k_anchor     per anchor: argmax gt, pos = (max>=0.7 | iou==hq[g] any g);
//                flag byte; npos; 4096-bin histogram of rbits23>>11
//   k_bin        per image: target bin + count-before (select-all if n<=128)
//   k_collect    positives in target bin -> fine 29-bit keys ((rbits&0x7ff)<<18|a)
//   k_tstar      per image (1 wave): exact 128th-smallest threshold (41-bit key)
//   k_count      positives with key<=T* -> per-gt counts
//   k_out        emit (pr, gt, valid, scores)
//
// IoU is fp-contract(off) IEEE per-op: identical bits across both IoU passes and
// matches XLA per-HLO rounding. partial-top4 buffer aliases flagg (dead after merge).

#pragma clang fp contract(off)

#define B_IMG 8
#define A_N 200000
#define G_N 64
#define K_TOP 4
#define MAX_POS 128
#define NBIN 4096
#define FINE_CAP 4096
#define AS 2048
#define NS 98   // ceil(200000/2048)

typedef unsigned long long u64;
typedef unsigned int u32;
typedef unsigned char u8;

__device__ __forceinline__ u32 rotl32(u32 v, int n) { return (v << n) | (v >> (32 - n)); }

__device__ __forceinline__ void tf_round(u32& x0, u32& x1, int r) {
  x0 += x1; x1 = rotl32(x1, r); x1 ^= x0;
}

__device__ __forceinline__ void threefry2x32(u32 k0, u32 k1, u32& x0, u32& x1) {
  u32 ks2 = 0x1BD11BDAu ^ k0 ^ k1;
  x0 += k0; x1 += k1;
  tf_round(x0,x1,13); tf_round(x0,x1,15); tf_round(x0,x1,26); tf_round(x0,x1,6);
  x0 += k1; x1 += ks2 + 1u;
  tf_round(x0,x1,17); tf_round(x0,x1,29); tf_round(x0,x1,16); tf_round(x0,x1,24);
  x0 += ks2; x1 += k0 + 2u;
  tf_round(x0,x1,13); tf_round(x0,x1,15); tf_round(x0,x1,26); tf_round(x0,x1,6);
  x0 += k0; x1 += k1 + 3u;
  tf_round(x0,x1,17); tf_round(x0,x1,29); tf_round(x0,x1,16); tf_round(x0,x1,24);
  x0 += k1; x1 += ks2 + 4u;
  tf_round(x0,x1,13); tf_round(x0,x1,15); tf_round(x0,x1,26); tf_round(x0,x1,6);
  x0 += ks2; x1 += k0 + 5u;
}

__device__ __forceinline__ void image_key(int b, u32& kb0, u32& kb1) {
  u32 x0 = 0u, x1 = (u32)b;
  threefry2x32(0u, 42u, x0, x1);
  kb0 = x0; kb1 = x1;
}

__device__ __forceinline__ u32 rbits_for(u32 k0, u32 k1, u32 a) {
  u32 x0 = 0u, x1 = a;
  threefry2x32(k0, k1, x0, x1);
  return x0 ^ x1;
}

__device__ __forceinline__ void conv_box(float4 bx, float& x0, float& y0,
                                         float& x1, float& y1, float& area) {
  #pragma clang fp contract(off)
  x0 = bx.x - 0.5f * bx.z;
  y0 = bx.y - 0.5f * bx.w;
  x1 = bx.x + 0.5f * bx.z;
  y1 = bx.y + 0.5f * bx.w;
  area = (x1 - x0) * (y1 - y0);
}

__device__ __forceinline__ float iou_pair(float ax0, float ay0, float ax1, float ay1, float aarea,
                                          float gx0, float gy0, float gx1, float gy1, float garea) {
  #pragma clang fp contract(off)
  float ltx = fmaxf(gx0, ax0), lty = fmaxf(gy0, ay0);
  float rbx = fminf(gx1, ax1), rby = fminf(gy1, ay1);
  float w = fmaxf(rbx - ltx, 0.0f), h = fmaxf(rby - lty, 0.0f);
  float inter = w * h;
  float uni = (garea + aarea) - inter;
  return inter / uni;
}

__device__ __forceinline__ void top4_insert(u64 (&top)[4], u64 key) {
  if (key > top[3]) {
    if (key > top[0])      { top[3]=top[2]; top[2]=top[1]; top[1]=top[0]; top[0]=key; }
    else if (key > top[1]) { top[3]=top[2]; top[2]=top[1]; top[1]=key; }
    else if (key > top[2]) { top[3]=top[2]; top[2]=key; }
    else                   { top[3]=key; }
  }
}

__device__ __forceinline__ void wave_merge_top4(u64 (&top)[4]) {
  for (int off = 32; off >= 1; off >>= 1) {
    u64 o[4];
    #pragma unroll
    for (int k = 0; k < 4; k++) o[k] = __shfl_down(top[k], (unsigned)off);
    u64 m[4]; int i = 0, j = 0;
    #pragma unroll
    for (int k = 0; k < 4; k++) m[k] = (top[i] >= o[j]) ? top[i++] : o[j++];
    #pragma unroll
    for (int k = 0; k < 4; k++) top[k] = m[k];
  }
}

// ---------------- Kernel 1a: per-(slice,b) partial top-4 for all gts ----------------
__launch_bounds__(256)
__global__ void k_top4_part(const float4* __restrict__ anchors, const float4* __restrict__ gt,
                            u64* __restrict__ partial) {
  const int b = blockIdx.y, s = blockIdx.x, t = threadIdx.x;
  const int wave = t >> 6, lane = t & 63;

  __shared__ float4 sxy[AS];
  __shared__ float  sar[AS];
  __shared__ float  sg[5][G_N];

  const int base = s * AS;
  const int cnt = min(AS, A_N - base);
  const float4* ab = anchors + (size_t)b * A_N + base;

  for (int j = t; j < cnt; j += 256) {
    float x0, y0, x1, y1, ar;
    conv_box(ab[j], x0, y0, x1, y1, ar);
    sxy[j] = make_float4(x0, y0, x1, y1);
    sar[j] = ar;
  }
  if (t < G_N) {
    float x0, y0, x1, y1, ar;
    conv_box(gt[(size_t)b * G_N + t], x0, y0, x1, y1, ar);
    sg[0][t] = x0; sg[1][t] = y0; sg[2][t] = x1; sg[3][t] = y1; sg[4][t] = ar;
  }
  __syncthreads();

  for (int g = wave; g < G_N; g += 4) {
    const float gx0 = sg[0][g], gy0 = sg[1][g], gx1 = sg[2][g], gy1 = sg[3][g], ga = sg[4][g];
    u64 top[4] = {0ull, 0ull, 0ull, 0ull};
    for (int j = lane; j < cnt; j += 64) {
      float4 x = sxy[j];
      float v = iou_pair(x.x, x.y, x.z, x.w, sar[j], gx0, gy0, gx1, gy1, ga);
      u32 aidx = (u32)(base + j);
      top4_insert(top, ((u64)__float_as_uint(v) << 32) | (u64)(~aidx));
    }
    wave_merge_top4(top);
    if (lane == 0) {
      u64* dst = partial + (((size_t)b * NS + s) * G_N + g) * 4;
      #pragma unroll
      for (int k = 0; k < 4; k++) dst[k] = top[k];
    }
  }
}

// ---------------- Kernel 1b: merge partials -> top4 ----------------
__launch_bounds__(64)
__global__ void k_top4_merge(const u64* __restrict__ partial, u64* __restrict__ top4) {
  const int b = blockIdx.y, g = blockIdx.x, lane = threadIdx.x;
  u64 top[4] = {0ull, 0ull, 0ull, 0ull};
  for (int i = lane; i < NS * 4; i += 64) {
    u64 key = partial[(((size_t)b * NS + (i >> 2)) * G_N + g) * 4 + (i & 3)];
    top4_insert(top, key);
  }
  wave_merge_top4(top);
  if (lane == 0) {
    u64* dst = top4 + ((size_t)b * G_N + g) * 4;
    #pragma unroll
    for (int k = 0; k < 4; k++) dst[k] = top[k];
  }
}

// ---------------- Kernel 2: per-anchor pass ----------------
__launch_bounds__(256)
__global__ void k_anchor(const float4* __restrict__ anchors, const float4* __restrict__ gt,
                         const u64* __restrict__ top4, u8* __restrict__ flagg,
                         u32* __restrict__ npos, u32* __restrict__ hist) {
  const int b = blockIdx.y;
  const int t = threadIdx.x;
  __shared__ float sgx0[64], sgy0[64], sgx1[64], sgy1[64], sga[64];
  __shared__ u32 shq[64];
  __shared__ u32 skey[2];

  if (t < 64) {
    float x0, y0, x1, y1, ar;
    conv_box(gt[(size_t)b * G_N + t], x0, y0, x1, y1, ar);
    sgx0[t] = x0; sgy0[t] = y0; sgx1[t] = x1; sgy1[t] = y1; sga[t] = ar;
    shq[t] = (u32)(top4[((size_t)b * G_N + t) * 4] >> 32);  // hq bits
  }
  if (t == 0) { u32 k0, k1; image_key(b, k0, k1); skey[0] = k0; skey[1] = k1; }
  __syncthreads();

  const int a = blockIdx.x * 256 + t;
  if (a >= A_N) return;

  float ax0, ay0, ax1, ay1, aar;
  conv_box(anchors[(size_t)b * A_N + a], ax0, ay0, ax1, ay1, aar);

  float bv = -1.0f;
  int g0 = 0;
  bool lq = false;
  for (int g = 0; g < 64; g++) {
    float i0 = iou_pair(ax0, ay0, ax1, ay1, aar,
                        sgx0[g], sgy0[g], sgx1[g], sgy1[g], sga[g]);
    if (i0 > bv) { bv = i0; g0 = g; }     // strict > keeps first max (jnp.argmax)
    lq |= (i0 == __uint_as_float(shq[g]));
  }
  bool pos = (bv >= 0.7f) || lq;
  flagg[(size_t)b * A_N + a] = (u8)((pos ? 0x40 : 0) | g0);
  if (pos) {
    atomicAdd(&npos[b], 1u);
    u32 bits = rbits_for(skey[0], skey[1], (u32)a);
    atomicAdd(&hist[b * NBIN + (int)(bits >> 20)], 1u);  // bin = rbits23 >> 11
  }
}

// ---------------- Kernel 3: per-image target bin ----------------
__launch_bounds__(256)
__global__ void k_bin(const u32* __restrict__ npos, const u32* __restrict__ hist,
                      int2* __restrict__ binsel) {
  const int b = blockIdx.x;
  const int t = threadIdx.x;
  __shared__ u32 part[256];
  const u32* hb = hist + b * NBIN;
  u32 local = 0;
  for (int j = 0; j < 16; j++) local += hb[t * 16 + j];
  part[t] = local;
  __syncthreads();
  if (t == 0) {
    if (npos[b] <= MAX_POS) {
      binsel[b] = make_int2(-1, 0);
    } else {
      u32 cum = 0; int chunk = 0;
      for (int i = 0; i < 256; i++) {
        if (cum + part[i] >= MAX_POS) { chunk = i; break; }
        cum += part[i];
      }
      int tb = chunk * 16; u32 before = cum;
      for (int j = 0; j < 16; j++) {
        u32 h = hb[chunk * 16 + j];
        if (before + h >= MAX_POS) { tb = chunk * 16 + j; break; }
        before += h;
      }
      binsel[b] = make_int2(tb, (int)before);
    }
  }
}

// ---------------- Kernel 4: collect fine candidates in target bin ----------------
__launch_bounds__(256)
__global__ void k_collect(const u8* __restrict__ flagg, const int2* __restrict__ binsel,
                          u32* __restrict__ fine, u32* __restrict__ fcnt) {
  const int b = blockIdx.y;
  __shared__ u32 sk0, sk1; __shared__ int stb;
  if (threadIdx.x == 0) {
    u32 k0, k1; image_key(b, k0, k1); sk0 = k0; sk1 = k1;
    stb = binsel[b].x;
  }
  __syncthreads();
  if (stb < 0) return;
  const int a = blockIdx.x * 256 + threadIdx.x;
  if (a >= A_N) return;
  u8 f = flagg[(size_t)b * A_N + a];
  if (!(f & 0x40)) return;
  u32 r23 = rbits_for(sk0, sk1, (u32)a) >> 9;
  if ((int)(r23 >> 11) != stb) return;
  u32 key = ((r23 & 0x7FFu) << 18) | (u32)a;   // 29-bit fine key
  u32 i = atomicAdd(&fcnt[b], 1u);
  if (i < FINE_CAP) fine[b * FINE_CAP + i] = key;
}

// ---------------- Kernel 5: exact 128th-smallest threshold (1 wave) ----------------
__launch_bounds__(64)
__global__ void k_tstar(const int2* __restrict__ binsel, const u32* __restrict__ fine,
                        const u32* __restrict__ fcnt, u64* __restrict__ Tstar) {
  const int b = blockIdx.x;
  const int lane = threadIdx.x;
  int2 bs = binsel[b];
  if (bs.x < 0) { if (lane == 0) Tstar[b] = ~0ull; return; }
  const int m = min((int)fcnt[b], FINE_CAP);
  const u32 need = (u32)(MAX_POS - bs.y);   // >= 1
  const u32* fb = fine + b * FINE_CAP;
  u32 lo = 0, hi = (1u << 29) - 1;
  while (lo < hi) {
    u32 mid = lo + ((hi - lo) >> 1);
    u32 c = 0;
    for (int j = lane; j < m; j += 64) c += (fb[j] <= mid) ? 1u : 0u;
    #pragma unroll
    for (int off = 32; off >= 1; off >>= 1) c += __shfl_xor(c, off);
    if (c >= need) hi = mid; else lo = mid + 1;   // uniform across wave
  }
  if (lane == 0) Tstar[b] = ((u64)(u32)bs.x << 29) | (u64)lo;   // 41-bit threshold
}

// ---------------- Kernel 6: per-gt counts of selected positives ----------------
__launch_bounds__(256)
__global__ void k_count(const u8* __restrict__ flagg, const u64* __restrict__ Tstar,
                        u32* __restrict__ cnt) {
  const int b = blockIdx.y;
  __shared__ u32 sk0, sk1; __shared__ u64 sT;
  if (threadIdx.x == 0) {
    u32 k0, k1; image_key(b, k0, k1); sk0 = k0; sk1 = k1;
    sT = Tstar[b];
  }
  __syncthreads();
  const int a = blockIdx.x * 256 + threadIdx.x;
  if (a >= A_N) return;
  u8 f = flagg[(size_t)b * A_N + a];
  if (!(f & 0x40)) return;
  u64 fk = 0;
  if (sT != ~0ull) {
    u32 r23 = rbits_for(sk0, sk1, (u32)a) >> 9;
    fk = ((u64)r23 << 18) | (u64)(u32)a;   // 41-bit full key
  }
  if (fk <= sT) atomicAdd(&cnt[b * G_N + (f & 63)], 1u);
}

// ---------------- Kernel 7: output ----------------
__launch_bounds__(64)
__global__ void k_out(const u64* __restrict__ top4, const u32* __restrict__ cnt,
                      float* __restrict__ out, int sec) {
  const int b = blockIdx.x;
  const int g = threadIdx.x;   // 64 threads
  const u32 c = min(cnt[b * G_N + g], (u32)K_TOP);
  const u64* t4 = top4 + ((size_t)b * G_N + g) * 4;
  #pragma unroll
  for (int k = 0; k < 4; k++) {
    u64 key = t4[k];
    u32 fb = (u32)(key >> 32);
    u32 aidx = ~(u32)key;
    bool valid = (u32)k < c;
    int o = b * (G_N * K_TOP) + g * K_TOP + k;
    out[0 * sec + o] = valid ? (float)aidx : -1.0f;          // pr_inds
    out[1 * sec + o] = valid ? (float)g : -1.0f;             // gt_inds
    out[2 * sec + o] = valid ? 1.0f : 0.0f;                  // valid mask
    out[3 * sec + o] = valid ? __uint_as_float(fb) : 0.0f;   // topk ious
  }
}

extern "C" void kernel_launch(void* const* d_in, const int* in_sizes, int n_in,
                              void* d_out, int out_size, void* d_ws, size_t ws_size,
                              hipStream_t stream) {
  const float4* anchors = (const float4*)d_in[0];  // [B, A, 4] cxcywh
  const float4* gt      = (const float4*)d_in[1];  // [B, G, 4] cxcywh
  float* out = (float*)d_out;                      // 4 x [B, G*K] concatenated

  // partial: B*NS*G*4*8 = 1,605,632 B; flagg (B*A = 1,600,000 B) ALIASES it —
  // partial is dead after k_top4_merge, flagg written only afterwards.
  char* ws = (char*)d_ws;
  u64*  top4    = (u64*)(ws);                      // 16384 B
  u64*  partial = (u64*)(ws + 16384);              // 1605632 B (shared region)
  u8*   flagg   = (u8*) (ws + 16384);              //   aliases partial
  int2* binsel  = (int2*)(ws + 1622016);           // 64 B
  u64*  Tstar   = (u64*)(ws + 1622080);            // 64 B
  u32*  fine    = (u32*)(ws + 1622144);            // 131072 B
  char* zr      = ws + 1753216;                    // zeroed region, 133184 B
  u32*  npos    = (u32*)(zr);                      // 32 B
  u32*  fcnt    = (u32*)(zr + 32);                 // 32 B
  u32*  cnt     = (u32*)(zr + 64);                 // 2048 B
  u32*  hist    = (u32*)(zr + 2112);               // 131072 B

  hipMemsetAsync(zr, 0, 133184, stream);

  const int ABLK = (A_N + 255) / 256;  // 782
  int sec = out_size / 4;              // 2048 = B*G*K

  k_top4_part <<<dim3(NS, B_IMG), 256, 0, stream>>>(anchors, gt, partial);
  k_top4_merge<<<dim3(G_N, B_IMG), 64, 0, stream>>>(partial, top4);
  k_anchor    <<<dim3(ABLK, B_IMG), 256, 0, stream>>>(anchors, gt, top4, flagg, npos, hist);
  k_bin       <<<dim3(B_IMG), 256, 0, stream>>>(npos, hist, binsel);
  k_collect   <<<dim3(ABLK, B_IMG), 256, 0, stream>>>(flagg, binsel, fine, fcnt);
  k_tstar     <<<dim3(B_IMG), 64, 0, stream>>>(binsel, fine, fcnt, Tstar);
  k_count     <<<dim3(ABLK, B_IMG), 256, 0, stream>>>(flagg, Tstar, cnt);
  k_out       <<<dim3(B_IMG), 64, 0, stream>>>(top4, cnt, out, sec);
}